// Round 1
// baseline (685.463 us; speedup 1.0000x reference)
//
#include <hip/hip_runtime.h>

// GCN: 4x (gcn_conv + relu) + global mean pool + linear out.
// N=100000 nodes, E=1000000 edges, G=4096 graphs, F_IN=9, H=64.
// Strategy:
//  - Build CSR (by dst) each call: deg histogram -> block scan -> scatter.
//  - dis[n] = rsqrt(in_deg+1)  (self-loop included).
//  - Layer 1: aggregate x (9 feats) first, then 9x64 transform (commute trick).
//  - Layers 2-4: m = dis[n]*(h@W) [LDS-tiled fp32 GEMM], then gather-aggregate
//    h' = relu(dis[n]*(m[n] + sum_nbr m[s]) + b), one wave per node, lane=feature.
//  - Output: y[n] = dot(h4[n], Wout); scalar segment-sum per graph; /count + bout.

static inline size_t align256(size_t x){ return (x + 255) & ~size_t(255); }

__global__ void k_zero(int* deg, float* gsum, int* gcount, int N, int G){
  int i = blockIdx.x*blockDim.x + threadIdx.x;
  if (i < N) deg[i] = 0;
  if (i < G){ gsum[i] = 0.f; gcount[i] = 0; }
}

__global__ void k_deg(const int* __restrict__ dst, const int* __restrict__ batch,
                      int* deg, int* gcount, int E, int N){
  int i = blockIdx.x*blockDim.x + threadIdx.x;
  if (i < E) atomicAdd(&deg[dst[i]], 1);
  if (i < N) atomicAdd(&gcount[batch[i]], 1);
}

__global__ void k_scanA(const int* __restrict__ deg, int* blockSums, int N){
  __shared__ int s[256];
  int t = threadIdx.x; int i = blockIdx.x*256 + t;
  s[t] = (i < N) ? deg[i] : 0;
  __syncthreads();
  for (int off=128; off>0; off>>=1){ if (t < off) s[t] += s[t+off]; __syncthreads(); }
  if (t==0) blockSums[blockIdx.x] = s[0];
}

// single-block exclusive scan of up to 512 block sums (NB=391 here)
__global__ void k_scanB(const int* __restrict__ blockSums, int* blockOffs, int NB){
  __shared__ int s[512];
  int t = threadIdx.x;
  int v = (t < NB) ? blockSums[t] : 0;
  s[t] = v; __syncthreads();
  for (int off=1; off<512; off<<=1){
    int add = (t>=off) ? s[t-off] : 0; __syncthreads();
    s[t] += add; __syncthreads();
  }
  if (t < NB) blockOffs[t] = s[t] - v;
}

__global__ void k_scanC(const int* __restrict__ deg, const int* __restrict__ blockOffs,
                        int* row_ptr, int* cursor, float* dis, int N){
  __shared__ int s[256];
  int t = threadIdx.x; int i = blockIdx.x*256 + t;
  int v = (i < N) ? deg[i] : 0;
  s[t] = v; __syncthreads();
  for (int off=1; off<256; off<<=1){
    int add = (t>=off) ? s[t-off] : 0; __syncthreads();
    s[t] += add; __syncthreads();
  }
  if (i < N){
    int row = blockOffs[blockIdx.x] + s[t] - v;   // exclusive
    row_ptr[i] = row; cursor[i] = row;
    dis[i] = rsqrtf((float)(v + 1));              // +1 self-loop; deg>=1
    if (i == N-1) row_ptr[N] = blockOffs[blockIdx.x] + s[t];
  }
}

__global__ void k_scatter(const int* __restrict__ src, const int* __restrict__ dst,
                          int* cursor, int* __restrict__ csr, int E){
  int i = blockIdx.x*blockDim.x + threadIdx.x;
  if (i < E){
    int d = dst[i];
    int pos = atomicAdd(&cursor[d], 1);
    csr[pos] = src[i];
  }
}

// layer-1 aggregation over raw x (9 features): thread per (node, feature)
__global__ void k_agg9(const float* __restrict__ x, const float* __restrict__ dis,
                       const int* __restrict__ row_ptr, const int* __restrict__ csr,
                       float* __restrict__ xagg, int N){
  int tid = blockIdx.x*blockDim.x + threadIdx.x;
  if (tid >= N*9) return;
  int n = tid/9, f = tid - n*9;
  float dn = dis[n];
  float acc = x[n*9+f]*dn;            // self-loop term (x[n]*dis[n])
  int s0 = row_ptr[n], s1 = row_ptr[n+1];
  for (int j = s0; j < s1; j++){
    int s = csr[j];
    acc = fmaf(x[s*9+f], dis[s], acc);
  }
  xagg[tid] = acc*dn;
}

// h1 = relu(xagg @ W1 + b1)   (9 -> 64)
__global__ void k_lin1(const float* __restrict__ xagg, const float* __restrict__ W1,
                       const float* __restrict__ b1, float* __restrict__ h, int N){
  __shared__ float Wl[576];
  __shared__ float bl[64];
  int t = threadIdx.x;
  for (int i = t; i < 576; i += 256) Wl[i] = W1[i];
  if (t < 64) bl[t] = b1[t];
  __syncthreads();
  int tid = blockIdx.x*256 + t;
  int n = tid >> 6, f = tid & 63;
  if (n >= N) return;
  float acc = bl[f];
  #pragma unroll
  for (int k = 0; k < 9; k++) acc = fmaf(xagg[n*9+k], Wl[k*64+f], acc);
  h[tid] = fmaxf(acc, 0.f);
}

// m[n] = dis[n] * (h[n] @ W)   (64 -> 64); 16-node tiles, float4 outputs/thread
__global__ __launch_bounds__(256) void k_lin64(
    const float* __restrict__ h, const float* __restrict__ W,
    const float* __restrict__ dis, float* __restrict__ m, int N){
  __shared__ __align__(16) float Wl[64*64];
  __shared__ float hl[16*65];          // +1 pad: conflict-free broadcast reads
  int t = threadIdx.x;
  for (int i = t; i < 4096; i += 256) Wl[i] = W[i];
  int tiles = (N + 15) >> 4;
  int nl = t >> 4, q = t & 15;
  const float4* W4 = (const float4*)Wl;
  for (int tile = blockIdx.x; tile < tiles; tile += gridDim.x){
    int n0 = tile << 4;
    __syncthreads();
    #pragma unroll
    for (int j = 0; j < 4; j++){
      int idx = t + j*256;                       // 0..1023 over 16 nodes x 64 feats
      int node = n0 + (idx >> 6);
      float v = (node < N) ? h[n0*64 + idx] : 0.f;
      hl[(idx>>6)*65 + (idx&63)] = v;
    }
    __syncthreads();
    int node = n0 + nl;
    if (node < N){
      float4 acc = {0.f,0.f,0.f,0.f};
      #pragma unroll
      for (int k = 0; k < 64; k++){
        float hv = hl[nl*65 + k];
        float4 w = W4[k*16 + q];
        acc.x = fmaf(hv, w.x, acc.x);
        acc.y = fmaf(hv, w.y, acc.y);
        acc.z = fmaf(hv, w.z, acc.z);
        acc.w = fmaf(hv, w.w, acc.w);
      }
      float s = dis[node];
      float4 o = {acc.x*s, acc.y*s, acc.z*s, acc.w*s};
      *(float4*)&m[n0*64 + t*4] = o;
    }
  }
}

// h'[n] = relu(dis[n]*(m[n] + sum_nbr m[s]) + b); one wave per node, lane = feature
__global__ void k_agg64(const float* __restrict__ m, const float* __restrict__ dis,
                        const float* __restrict__ b,
                        const int* __restrict__ row_ptr, const int* __restrict__ csr,
                        float* __restrict__ h, int N){
  int lane = threadIdx.x & 63;
  int n = (blockIdx.x*blockDim.x + threadIdx.x) >> 6;
  if (n >= N) return;
  float bl = b[lane];
  int s0 = row_ptr[n], s1 = row_ptr[n+1];
  float acc = m[n*64 + lane];                    // self-loop term
  for (int j = s0; j < s1; j++){
    int s = csr[j];
    acc += m[s*64 + lane];
  }
  float v = fmaf(acc, dis[n], bl);
  h[n*64 + lane] = fmaxf(v, 0.f);
}

// per-node dot(h, Wout) -> wave reduce -> atomic segment add
__global__ void k_out(const float* __restrict__ h, const float* __restrict__ Wout,
                      const int* __restrict__ batch, float* gsum, int N){
  int lane = threadIdx.x & 63;
  int n = (blockIdx.x*blockDim.x + threadIdx.x) >> 6;
  if (n >= N) return;
  float p = h[n*64 + lane]*Wout[lane];
  #pragma unroll
  for (int off = 32; off > 0; off >>= 1) p += __shfl_xor(p, off, 64);
  if (lane == 0) atomicAdd(&gsum[batch[n]], p);
}

__global__ void k_final(const float* __restrict__ gsum, const int* __restrict__ gcount,
                        const float* __restrict__ bout, float* __restrict__ out, int G){
  int g = blockIdx.x*blockDim.x + threadIdx.x;
  if (g < G){
    int c = gcount[g];
    out[g] = gsum[g]/(float)(c > 0 ? c : 1) + bout[0];
  }
}

extern "C" void kernel_launch(void* const* d_in, const int* in_sizes, int n_in,
                              void* d_out, int out_size, void* d_ws, size_t ws_size,
                              hipStream_t stream){
  const float* x    = (const float*)d_in[0];
  const int*   ei   = (const int*)d_in[1];
  const int*   batch= (const int*)d_in[2];
  const float* W1 = (const float*)d_in[3];  const float* b1 = (const float*)d_in[4];
  const float* W2 = (const float*)d_in[5];  const float* b2 = (const float*)d_in[6];
  const float* W3 = (const float*)d_in[7];  const float* b3 = (const float*)d_in[8];
  const float* W4 = (const float*)d_in[9];  const float* b4 = (const float*)d_in[10];
  const float* Wout = (const float*)d_in[11]; const float* bout = (const float*)d_in[12];
  float* out = (float*)d_out;

  const int N = in_sizes[0]/9;
  const int E = in_sizes[1]/2;
  const int G = out_size;
  const int* src = ei;        // edge_index[0]
  const int* dst = ei + E;    // edge_index[1]

  char* ws = (char*)d_ws;
  size_t off = 0;
  auto alloc = [&](size_t bytes){ void* p = ws + off; off = align256(off + bytes); return p; };
  int*   deg      = (int*)  alloc((size_t)N*4);
  int*   row_ptr  = (int*)  alloc((size_t)(N+1)*4);
  int*   cursor   = (int*)  alloc((size_t)N*4);
  int*   csr      = (int*)  alloc((size_t)E*4);
  float* dis      = (float*)alloc((size_t)N*4);
  const int NB = (N + 255)/256;   // 391 (< 512 required by k_scanB)
  int*   blockSums= (int*)  alloc((size_t)NB*4);
  int*   blockOffs= (int*)  alloc((size_t)NB*4);
  float* gsum     = (float*)alloc((size_t)G*4);
  int*   gcount   = (int*)  alloc((size_t)G*4);
  float* bufA     = (float*)alloc((size_t)N*64*4);
  float* bufB     = (float*)alloc((size_t)N*64*4);
  float* xagg     = bufB;   // layer-1 9-feature aggregate aliases bufB

  const int EN = (E > N) ? E : N;

  k_zero   <<<(N+255)/256, 256, 0, stream>>>(deg, gsum, gcount, N, G);
  k_deg    <<<(EN+255)/256, 256, 0, stream>>>(dst, batch, deg, gcount, E, N);
  k_scanA  <<<NB, 256, 0, stream>>>(deg, blockSums, N);
  k_scanB  <<<1, 512, 0, stream>>>(blockSums, blockOffs, NB);
  k_scanC  <<<NB, 256, 0, stream>>>(deg, blockOffs, row_ptr, cursor, dis, N);
  k_scatter<<<(E+255)/256, 256, 0, stream>>>(src, dst, cursor, csr, E);

  // layer 1: aggregate (9 feats) then transform
  k_agg9<<<(N*9+255)/256, 256, 0, stream>>>(x, dis, row_ptr, csr, xagg, N);
  k_lin1<<<(N*64+255)/256, 256, 0, stream>>>(xagg, W1, b1, bufA, N);

  // layers 2-4: transform (with dis premult) then aggregate
  const float* Ws[3] = {W2, W3, W4};
  const float* bs[3] = {b2, b3, b4};
  for (int l = 0; l < 3; l++){
    k_lin64<<<1792, 256, 0, stream>>>(bufA, Ws[l], dis, bufB, N);
    k_agg64<<<(N*64+255)/256, 256, 0, stream>>>(bufB, dis, bs[l], row_ptr, csr, bufA, N);
  }

  // epilogue: per-node projection, graph mean, bias
  k_out  <<<(N*64+255)/256, 256, 0, stream>>>(bufA, Wout, batch, gsum, N);
  k_final<<<(G+255)/256, 256, 0, stream>>>(gsum, gcount, bout, out, G);
}

// Round 2
// 492.719 us; speedup vs baseline: 1.3912x; 1.3912x over previous
//
#include <hip/hip_runtime.h>

// GCN: 4x (gcn_conv + relu) + global mean pool + linear out.
// N=100000 nodes, E=1000000 edges, G=4096 graphs, F_IN=9, H=64.
// R1: k_agg64 restructured for memory-level parallelism: wave = 1 node,
//     4 subgroups x 16 lanes, each subgroup gathers one 256B m-row as float4,
//     unrolled x2 => 8 row-loads in flight (was ~1 serial).  Layer-4 agg fused
//     with output projection (k_out removed).  k_agg9 premultiplied + unroll-4.

static inline size_t align256(size_t x){ return (x + 255) & ~size_t(255); }

__global__ void k_zero(int* deg, float* gsum, int* gcount, int N, int G){
  int i = blockIdx.x*blockDim.x + threadIdx.x;
  if (i < N) deg[i] = 0;
  if (i < G){ gsum[i] = 0.f; gcount[i] = 0; }
}

__global__ void k_deg(const int* __restrict__ dst, const int* __restrict__ batch,
                      int* deg, int* gcount, int E, int N){
  int i = blockIdx.x*blockDim.x + threadIdx.x;
  if (i < E) atomicAdd(&deg[dst[i]], 1);
  if (i < N) atomicAdd(&gcount[batch[i]], 1);
}

__global__ void k_scanA(const int* __restrict__ deg, int* blockSums, int N){
  __shared__ int s[256];
  int t = threadIdx.x; int i = blockIdx.x*256 + t;
  s[t] = (i < N) ? deg[i] : 0;
  __syncthreads();
  for (int off=128; off>0; off>>=1){ if (t < off) s[t] += s[t+off]; __syncthreads(); }
  if (t==0) blockSums[blockIdx.x] = s[0];
}

// single-block exclusive scan of up to 512 block sums (NB=391 here)
__global__ void k_scanB(const int* __restrict__ blockSums, int* blockOffs, int NB){
  __shared__ int s[512];
  int t = threadIdx.x;
  int v = (t < NB) ? blockSums[t] : 0;
  s[t] = v; __syncthreads();
  for (int off=1; off<512; off<<=1){
    int add = (t>=off) ? s[t-off] : 0; __syncthreads();
    s[t] += add; __syncthreads();
  }
  if (t < NB) blockOffs[t] = s[t] - v;
}

__global__ void k_scanC(const int* __restrict__ deg, const int* __restrict__ blockOffs,
                        int* row_ptr, int* cursor, float* dis, int N){
  __shared__ int s[256];
  int t = threadIdx.x; int i = blockIdx.x*256 + t;
  int v = (i < N) ? deg[i] : 0;
  s[t] = v; __syncthreads();
  for (int off=1; off<256; off<<=1){
    int add = (t>=off) ? s[t-off] : 0; __syncthreads();
    s[t] += add; __syncthreads();
  }
  if (i < N){
    int row = blockOffs[blockIdx.x] + s[t] - v;   // exclusive
    row_ptr[i] = row; cursor[i] = row;
    dis[i] = rsqrtf((float)(v + 1));              // +1 self-loop; deg>=1
    if (i == N-1) row_ptr[N] = blockOffs[blockIdx.x] + s[t];
  }
}

__global__ void k_scatter(const int* __restrict__ src, const int* __restrict__ dst,
                          int* cursor, int* __restrict__ csr, int E){
  int i = blockIdx.x*blockDim.x + threadIdx.x;
  if (i < E){
    int d = dst[i];
    int pos = atomicAdd(&cursor[d], 1);
    csr[pos] = src[i];
  }
}

// xs[n] = x[n] * dis[n]  (premultiply so the gather loop has one load per edge)
__global__ void k_premul(const float* __restrict__ x, const float* __restrict__ dis,
                         float* __restrict__ xs, int N){
  int i = blockIdx.x*blockDim.x + threadIdx.x;
  if (i < N*9) xs[i] = x[i]*dis[i/9];
}

// layer-1 aggregation over xs (9 features): thread per (node, feature), unroll-4 MLP
__global__ void k_agg9(const float* __restrict__ xs, const float* __restrict__ dis,
                       const int* __restrict__ row_ptr, const int* __restrict__ csr,
                       float* __restrict__ xagg, int N){
  int tid = blockIdx.x*blockDim.x + threadIdx.x;
  if (tid >= N*9) return;
  int n = tid/9, f = tid - n*9;
  float dn = dis[n];
  int s0 = row_ptr[n], s1 = row_ptr[n+1];
  float a0 = xs[tid];                 // self-loop term (x[n]*dis[n])
  float a1 = 0.f, a2 = 0.f, a3 = 0.f;
  int j = s0;
  for (; j + 3 < s1; j += 4){
    int e0 = csr[j], e1 = csr[j+1], e2 = csr[j+2], e3 = csr[j+3];
    a0 += xs[e0*9+f];
    a1 += xs[e1*9+f];
    a2 += xs[e2*9+f];
    a3 += xs[e3*9+f];
  }
  for (; j < s1; j++) a0 += xs[csr[j]*9+f];
  xagg[tid] = ((a0+a1)+(a2+a3))*dn;
}

// h1 = relu(xagg @ W1 + b1)   (9 -> 64)
__global__ void k_lin1(const float* __restrict__ xagg, const float* __restrict__ W1,
                       const float* __restrict__ b1, float* __restrict__ h, int N){
  __shared__ float Wl[576];
  __shared__ float bl[64];
  int t = threadIdx.x;
  for (int i = t; i < 576; i += 256) Wl[i] = W1[i];
  if (t < 64) bl[t] = b1[t];
  __syncthreads();
  int tid = blockIdx.x*256 + t;
  int n = tid >> 6, f = tid & 63;
  if (n >= N) return;
  float acc = bl[f];
  #pragma unroll
  for (int k = 0; k < 9; k++) acc = fmaf(xagg[n*9+k], Wl[k*64+f], acc);
  h[tid] = fmaxf(acc, 0.f);
}

// m[n] = dis[n] * (h[n] @ W)   (64 -> 64); 16-node tiles, float4 outputs/thread
__global__ __launch_bounds__(256) void k_lin64(
    const float* __restrict__ h, const float* __restrict__ W,
    const float* __restrict__ dis, float* __restrict__ m, int N){
  __shared__ __align__(16) float Wl[64*64];
  __shared__ float hl[16*65];          // +1 pad: conflict-free broadcast reads
  int t = threadIdx.x;
  for (int i = t; i < 4096; i += 256) Wl[i] = W[i];
  int tiles = (N + 15) >> 4;
  int nl = t >> 4, q = t & 15;
  const float4* W4 = (const float4*)Wl;
  for (int tile = blockIdx.x; tile < tiles; tile += gridDim.x){
    int n0 = tile << 4;
    __syncthreads();
    #pragma unroll
    for (int j = 0; j < 4; j++){
      int idx = t + j*256;                       // 0..1023 over 16 nodes x 64 feats
      int node = n0 + (idx >> 6);
      float v = (node < N) ? h[n0*64 + idx] : 0.f;
      hl[(idx>>6)*65 + (idx&63)] = v;
    }
    __syncthreads();
    int node = n0 + nl;
    if (node < N){
      float4 acc = {0.f,0.f,0.f,0.f};
      #pragma unroll
      for (int k = 0; k < 64; k++){
        float hv = hl[nl*65 + k];
        float4 w = W4[k*16 + q];
        acc.x = fmaf(hv, w.x, acc.x);
        acc.y = fmaf(hv, w.y, acc.y);
        acc.z = fmaf(hv, w.z, acc.z);
        acc.w = fmaf(hv, w.w, acc.w);
      }
      float s = dis[node];
      float4 o = {acc.x*s, acc.y*s, acc.z*s, acc.w*s};
      *(float4*)&m[n0*64 + t*4] = o;
    }
  }
}

// h'[n] = relu(dis[n]*(m[n] + sum_nbr m[s]) + b)
// wave = 1 node; 4 subgroups x 16 lanes; subgroup gathers one 256B row (float4/lane);
// unroll x2 => 8 independent row-loads in flight per wave.
__global__ __launch_bounds__(256) void k_agg64(
    const float* __restrict__ m, const float* __restrict__ dis,
    const float* __restrict__ b,
    const int* __restrict__ row_ptr, const int* __restrict__ csr,
    float* __restrict__ h, int N){
  int lane = threadIdx.x & 63;
  int n = (blockIdx.x*blockDim.x + threadIdx.x) >> 6;
  if (n >= N) return;
  int sub = lane >> 4, q = lane & 15;
  const float4* m4 = (const float4*)m;
  float4 self = m4[n*16 + q];
  int s0 = row_ptr[n], s1 = row_ptr[n+1];
  float ax = 0.f, ay = 0.f, az = 0.f, aw = 0.f;
  int j = s0 + sub;
  for (; j + 4 < s1; j += 8){
    int e0 = csr[j], e1 = csr[j+4];
    float4 a = m4[e0*16 + q];
    float4 c = m4[e1*16 + q];
    ax += a.x; ay += a.y; az += a.z; aw += a.w;
    ax += c.x; ay += c.y; az += c.z; aw += c.w;
  }
  if (j < s1){
    float4 a = m4[csr[j]*16 + q];
    ax += a.x; ay += a.y; az += a.z; aw += a.w;
  }
  // combine the 4 subgroups (lane bits 4,5)
  ax += __shfl_xor(ax,16,64); ay += __shfl_xor(ay,16,64);
  az += __shfl_xor(az,16,64); aw += __shfl_xor(aw,16,64);
  ax += __shfl_xor(ax,32,64); ay += __shfl_xor(ay,32,64);
  az += __shfl_xor(az,32,64); aw += __shfl_xor(aw,32,64);
  float dn = dis[n];
  const float4* b4 = (const float4*)b;
  float4 bb = b4[q];
  float4 v;
  v.x = fmaxf(fmaf(ax + self.x, dn, bb.x), 0.f);
  v.y = fmaxf(fmaf(ay + self.y, dn, bb.y), 0.f);
  v.z = fmaxf(fmaf(az + self.z, dn, bb.z), 0.f);
  v.w = fmaxf(fmaf(aw + self.w, dn, bb.w), 0.f);
  if (sub == 0) ((float4*)h)[n*16 + q] = v;
}

// layer-4 aggregation fused with output projection: per-node dot(h4, Wout)
// -> wave reduce -> atomic segment add.  No h store at all.
__global__ __launch_bounds__(256) void k_agg64_out(
    const float* __restrict__ m, const float* __restrict__ dis,
    const float* __restrict__ b, const float* __restrict__ Wout,
    const int* __restrict__ batch,
    const int* __restrict__ row_ptr, const int* __restrict__ csr,
    float* gsum, int N){
  int lane = threadIdx.x & 63;
  int n = (blockIdx.x*blockDim.x + threadIdx.x) >> 6;
  if (n >= N) return;
  int sub = lane >> 4, q = lane & 15;
  const float4* m4 = (const float4*)m;
  float4 self = m4[n*16 + q];
  int s0 = row_ptr[n], s1 = row_ptr[n+1];
  float ax = 0.f, ay = 0.f, az = 0.f, aw = 0.f;
  int j = s0 + sub;
  for (; j + 4 < s1; j += 8){
    int e0 = csr[j], e1 = csr[j+4];
    float4 a = m4[e0*16 + q];
    float4 c = m4[e1*16 + q];
    ax += a.x; ay += a.y; az += a.z; aw += a.w;
    ax += c.x; ay += c.y; az += c.z; aw += c.w;
  }
  if (j < s1){
    float4 a = m4[csr[j]*16 + q];
    ax += a.x; ay += a.y; az += a.z; aw += a.w;
  }
  ax += __shfl_xor(ax,16,64); ay += __shfl_xor(ay,16,64);
  az += __shfl_xor(az,16,64); aw += __shfl_xor(aw,16,64);
  ax += __shfl_xor(ax,32,64); ay += __shfl_xor(ay,32,64);
  az += __shfl_xor(az,32,64); aw += __shfl_xor(aw,32,64);
  float dn = dis[n];
  const float4* b4 = (const float4*)b;
  float4 bb = b4[q];
  float4 v;
  v.x = fmaxf(fmaf(ax + self.x, dn, bb.x), 0.f);
  v.y = fmaxf(fmaf(ay + self.y, dn, bb.y), 0.f);
  v.z = fmaxf(fmaf(az + self.z, dn, bb.z), 0.f);
  v.w = fmaxf(fmaf(aw + self.w, dn, bb.w), 0.f);
  const float4* Wo4 = (const float4*)Wout;
  float4 wo = Wo4[q];
  float p = v.x*wo.x + v.y*wo.y + v.z*wo.z + v.w*wo.w;
  p += __shfl_xor(p,1,64); p += __shfl_xor(p,2,64);
  p += __shfl_xor(p,4,64); p += __shfl_xor(p,8,64);
  if (lane == 0) atomicAdd(&gsum[batch[n]], p);
}

__global__ void k_final(const float* __restrict__ gsum, const int* __restrict__ gcount,
                        const float* __restrict__ bout, float* __restrict__ out, int G){
  int g = blockIdx.x*blockDim.x + threadIdx.x;
  if (g < G){
    int c = gcount[g];
    out[g] = gsum[g]/(float)(c > 0 ? c : 1) + bout[0];
  }
}

extern "C" void kernel_launch(void* const* d_in, const int* in_sizes, int n_in,
                              void* d_out, int out_size, void* d_ws, size_t ws_size,
                              hipStream_t stream){
  const float* x    = (const float*)d_in[0];
  const int*   ei   = (const int*)d_in[1];
  const int*   batch= (const int*)d_in[2];
  const float* W1 = (const float*)d_in[3];  const float* b1 = (const float*)d_in[4];
  const float* W2 = (const float*)d_in[5];  const float* b2 = (const float*)d_in[6];
  const float* W3 = (const float*)d_in[7];  const float* b3 = (const float*)d_in[8];
  const float* W4 = (const float*)d_in[9];  const float* b4 = (const float*)d_in[10];
  const float* Wout = (const float*)d_in[11]; const float* bout = (const float*)d_in[12];
  float* out = (float*)d_out;

  const int N = in_sizes[0]/9;
  const int E = in_sizes[1]/2;
  const int G = out_size;
  const int* src = ei;        // edge_index[0]
  const int* dst = ei + E;    // edge_index[1]

  char* ws = (char*)d_ws;
  size_t off = 0;
  auto alloc = [&](size_t bytes){ void* p = ws + off; off = align256(off + bytes); return p; };
  int*   deg      = (int*)  alloc((size_t)N*4);
  int*   row_ptr  = (int*)  alloc((size_t)(N+1)*4);
  int*   cursor   = (int*)  alloc((size_t)N*4);
  int*   csr      = (int*)  alloc((size_t)E*4);
  float* dis      = (float*)alloc((size_t)N*4);
  const int NB = (N + 255)/256;   // 391 (< 512 required by k_scanB)
  int*   blockSums= (int*)  alloc((size_t)NB*4);
  int*   blockOffs= (int*)  alloc((size_t)NB*4);
  float* gsum     = (float*)alloc((size_t)G*4);
  int*   gcount   = (int*)  alloc((size_t)G*4);
  float* bufA     = (float*)alloc((size_t)N*64*4);
  float* bufB     = (float*)alloc((size_t)N*64*4);
  float* xagg     = bufB;   // layer-1 9-feature aggregate aliases bufB
  float* xs       = bufA;   // premultiplied x aliases bufA (freed by k_lin1 write)

  const int EN = (E > N) ? E : N;

  k_zero   <<<(N+255)/256, 256, 0, stream>>>(deg, gsum, gcount, N, G);
  k_deg    <<<(EN+255)/256, 256, 0, stream>>>(dst, batch, deg, gcount, E, N);
  k_scanA  <<<NB, 256, 0, stream>>>(deg, blockSums, N);
  k_scanB  <<<1, 512, 0, stream>>>(blockSums, blockOffs, NB);
  k_scanC  <<<NB, 256, 0, stream>>>(deg, blockOffs, row_ptr, cursor, dis, N);
  k_scatter<<<(E+255)/256, 256, 0, stream>>>(src, dst, cursor, csr, E);

  // layer 1: premultiply, aggregate (9 feats), then transform
  k_premul<<<(N*9+255)/256, 256, 0, stream>>>(x, dis, xs, N);
  k_agg9  <<<(N*9+255)/256, 256, 0, stream>>>(xs, dis, row_ptr, csr, xagg, N);
  k_lin1  <<<(N*64+255)/256, 256, 0, stream>>>(xagg, W1, b1, bufA, N);

  // layers 2-3: transform (with dis premult) then aggregate
  const float* Ws[2] = {W2, W3};
  const float* bs[2] = {b2, b3};
  for (int l = 0; l < 2; l++){
    k_lin64<<<1792, 256, 0, stream>>>(bufA, Ws[l], dis, bufB, N);
    k_agg64<<<(N*64+255)/256, 256, 0, stream>>>(bufB, dis, bs[l], row_ptr, csr, bufA, N);
  }

  // layer 4: transform, then aggregation fused with output projection + pool
  k_lin64<<<1792, 256, 0, stream>>>(bufA, W4, dis, bufB, N);
  k_agg64_out<<<(N*64+255)/256, 256, 0, stream>>>(bufB, dis, b4, Wout, batch,
                                                  row_ptr, csr, gsum, N);

  k_final<<<(G+255)/256, 256, 0, stream>>>(gsum, gcount, bout, out, G);
}